// Round 3
// baseline (634.764 us; speedup 1.0000x reference)
//
#include <hip/hip_runtime.h>
#include <hip/hip_bf16.h>

// GAT (2-layer, 8-head) on gfx950. Inputs f32 (adj int32), outputs f32.
// d_out = [h2: 2048*512 | att1: 8*2048*2048 | att2: 8*2048*2048] float32.

typedef __attribute__((ext_vector_type(8))) short bf16x8;
typedef __attribute__((ext_vector_type(4))) float f32x4;
typedef __attribute__((ext_vector_type(8))) float f32x8;

__device__ __forceinline__ float bf2f(unsigned short u) {
    return __uint_as_float(((unsigned int)u) << 16);
}
__device__ __forceinline__ unsigned short f2bf(float f) {
    __hip_bfloat16 h = __float2bfloat16(f);
    return __builtin_bit_cast(unsigned short, h);
}
__device__ __forceinline__ float elu1(float x) { return x > 0.f ? x : expm1f(x); }

// ---------------------------------------------------------------------------
// Reorder W [8][512][64] (f32) into split-bf16 MFMA B-fragment packing:
// Wp{Hi,Lo}[h][kb][col][k&31], k = kb*32 + (quad*8+j). 262144 elements.
// ---------------------------------------------------------------------------
__global__ __launch_bounds__(256) void reorder_w_kernel(
    const float* __restrict__ W, unsigned short* __restrict__ WpHi,
    unsigned short* __restrict__ WpLo) {
    int i = blockIdx.x * 256 + threadIdx.x;  // exactly 262144 threads
    int o = i & 63;
    int k = (i >> 6) & 511;
    int h = i >> 15;
    float v = W[i];
    unsigned short hi = f2bf(v);
    unsigned short lo = f2bf(v - bf2f(hi));
    long idx = (((h * 16) + (k >> 5)) * 64 + o) * 32 + (k & 31);
    WpHi[idx] = hi;
    WpLo[idx] = lo;
}

// ---------------------------------------------------------------------------
// GEMM1: Wh[h] = A[2048][512](f32) @ W[h][512][64], split-bf16 (3 MFMAs).
// Stores Wh f32 plain [h][2048][64] + split fragment-packed bf16 WhpHi/Lo.
// Block: 256 thr = 4 waves; wave w covers rows [mt*64+w*16, +16), 64 cols.
// ---------------------------------------------------------------------------
__global__ __launch_bounds__(256) void gemm1_kernel(
    const float* __restrict__ A,
    const unsigned short* __restrict__ BpHi, const unsigned short* __restrict__ BpLo,
    float* __restrict__ WhPlain, unsigned short* __restrict__ WhpHi,
    unsigned short* __restrict__ WhpLo) {
    const int bx   = blockIdx.x;   // 256 = 8 heads * 32 mtiles
    const int h    = bx >> 5;
    const int mt   = bx & 31;
    const int tid  = threadIdx.x;
    const int wave = tid >> 6;
    const int lane = tid & 63;
    const int quad = lane >> 4;
    const int m16  = lane & 15;
    const int row0 = mt * 64 + wave * 16;

    // A fragment: (m=lane&15, k=quad*8+j), 8 consecutive f32 per lane.
    const float* Arow = A + (long)(row0 + m16) * 512 + quad * 8;
    const long boff = ((long)h * 16 * 64 + m16) * 32 + quad * 8;
    const unsigned short* BH = BpHi + boff;
    const unsigned short* BL = BpLo + boff;

    f32x4 acc[4];
#pragma unroll
    for (int t = 0; t < 4; ++t)
#pragma unroll
        for (int r = 0; r < 4; ++r) acc[t][r] = 0.f;

    for (int kb = 0; kb < 16; ++kb) {
        const float* ap = Arow + kb * 32;
        bf16x8 ahi, alo;
#pragma unroll
        for (int j = 0; j < 8; ++j) {
            float v = ap[j];
            unsigned short hv = f2bf(v);
            ahi[j] = (short)hv;
            alo[j] = (short)f2bf(v - bf2f(hv));
        }
        const unsigned short* bh0 = BH + (long)kb * 2048;  // 64 cols * 32
        const unsigned short* bl0 = BL + (long)kb * 2048;
#pragma unroll
        for (int t = 0; t < 4; ++t) {
            bf16x8 bh = *reinterpret_cast<const bf16x8*>(bh0 + t * 512);
            bf16x8 bl = *reinterpret_cast<const bf16x8*>(bl0 + t * 512);
            acc[t] = __builtin_amdgcn_mfma_f32_16x16x32_bf16(alo, bh, acc[t], 0, 0, 0);
            acc[t] = __builtin_amdgcn_mfma_f32_16x16x32_bf16(ahi, bl, acc[t], 0, 0, 0);
            acc[t] = __builtin_amdgcn_mfma_f32_16x16x32_bf16(ahi, bh, acc[t], 0, 0, 0);
        }
    }

    // C/D: col = lane&15 (+16*t), row = quad*4 + r.
#pragma unroll
    for (int t = 0; t < 4; ++t) {
        const int col = t * 16 + m16;
#pragma unroll
        for (int r = 0; r < 4; ++r) {
            const int row = row0 + quad * 4 + r;
            const float v = acc[t][r];
            WhPlain[((h * 2048 + row) << 6) + col] = v;
            long idx = (((h * 64 + (row >> 5)) * 64 + col) << 5) + (row & 31);
            unsigned short hv = f2bf(v);
            WhpHi[idx] = hv;
            WhpLo[idx] = f2bf(v - bf2f(hv));
        }
    }
}

// ---------------------------------------------------------------------------
// GEMM2: h_prime[h] = att[h][2048][2048](f32) @ Wh[h][2048][64], split-bf16
// on both operands (3 MFMAs). Out[row*512 + h*64 + col] = elu(elu(acc)), f32.
// ---------------------------------------------------------------------------
__global__ __launch_bounds__(256) void gemm2_kernel(
    const float* __restrict__ Att,
    const unsigned short* __restrict__ WhpHi, const unsigned short* __restrict__ WhpLo,
    float* __restrict__ Out) {
    const int bx   = blockIdx.x;   // 256 = 8 heads * 32 mtiles
    const int h    = bx >> 5;
    const int mt   = bx & 31;
    const int tid  = threadIdx.x;
    const int wave = tid >> 6;
    const int lane = tid & 63;
    const int quad = lane >> 4;
    const int m16  = lane & 15;
    const int row0 = mt * 64 + wave * 16;

    const float* Arow = Att + (long)h * 4194304 + (long)(row0 + m16) * 2048 + quad * 8;
    const long boff = ((long)h * 64 * 64 + m16) * 32 + quad * 8;
    const unsigned short* BH = WhpHi + boff;
    const unsigned short* BL = WhpLo + boff;

    f32x4 acc[4];
#pragma unroll
    for (int t = 0; t < 4; ++t)
#pragma unroll
        for (int r = 0; r < 4; ++r) acc[t][r] = 0.f;

    for (int kb = 0; kb < 64; ++kb) {
        const float* ap = Arow + kb * 32;
        bf16x8 ahi, alo;
#pragma unroll
        for (int j = 0; j < 8; ++j) {
            float v = ap[j];
            unsigned short hv = f2bf(v);
            ahi[j] = (short)hv;
            alo[j] = (short)f2bf(v - bf2f(hv));
        }
        const unsigned short* bh0 = BH + (long)kb * 2048;
        const unsigned short* bl0 = BL + (long)kb * 2048;
#pragma unroll
        for (int t = 0; t < 4; ++t) {
            bf16x8 bh = *reinterpret_cast<const bf16x8*>(bh0 + t * 512);
            bf16x8 bl = *reinterpret_cast<const bf16x8*>(bl0 + t * 512);
            acc[t] = __builtin_amdgcn_mfma_f32_16x16x32_bf16(alo, bh, acc[t], 0, 0, 0);
            acc[t] = __builtin_amdgcn_mfma_f32_16x16x32_bf16(ahi, bl, acc[t], 0, 0, 0);
            acc[t] = __builtin_amdgcn_mfma_f32_16x16x32_bf16(ahi, bh, acc[t], 0, 0, 0);
        }
    }

#pragma unroll
    for (int t = 0; t < 4; ++t) {
        const int col = t * 16 + m16;
#pragma unroll
        for (int r = 0; r < 4; ++r) {
            const int row = row0 + quad * 4 + r;
            Out[(row << 9) + (h << 6) + col] = elu1(elu1(acc[t][r]));
        }
    }
}

// ---------------------------------------------------------------------------
// s1[h,n] = Wh[h,n,:]·a[h,0:64], s2[h,n] = Wh[h,n,:]·a[h,64:128]  (all f32)
// ---------------------------------------------------------------------------
__global__ __launch_bounds__(256) void s_kernel(
    const float* __restrict__ Wh, const float* __restrict__ a,
    float* __restrict__ s1, float* __restrict__ s2) {
    int i = blockIdx.x * 256 + threadIdx.x;  // 16384 = 8*2048
    int h = i >> 11;
    const float* row = Wh + (long)i * 64;
    const float* ah = a + (h << 7);
    float acc1 = 0.f, acc2 = 0.f;
#pragma unroll
    for (int o = 0; o < 64; ++o) {
        float wv = row[o];
        acc1 = fmaf(wv, ah[o], acc1);
        acc2 = fmaf(wv, ah[64 + o], acc2);
    }
    s1[i] = acc1;
    s2[i] = acc2;
}

// ---------------------------------------------------------------------------
// Row softmax: block bx = h*2048 + i. e_j = lrelu(s1[i]+s2[j]) masked by adj,
// softmax over j, write f32 att row. 256 threads x 8 j's each.
// ---------------------------------------------------------------------------
__global__ __launch_bounds__(256) void softmax_kernel(
    const float* __restrict__ s1, const float* __restrict__ s2,
    const int* __restrict__ adj, float* __restrict__ att) {
    const int bx = blockIdx.x;       // [0, 16384)
    const int h = bx >> 11;
    const int i = bx & 2047;
    const int tid = threadIdx.x;
    const int j0 = tid * 8;

    const float s1i = s1[bx];
    const float* s2h = s2 + (h << 11);
    const int* arow = adj + (long)i * 2048;

    float e[8];
    float mx = -INFINITY;
#pragma unroll
    for (int u = 0; u < 8; ++u) {
        int j = j0 + u;
        float ev = s1i + s2h[j];
        ev = ev > 0.f ? ev : 0.2f * ev;
        e[u] = (arow[j] > 0) ? ev : -INFINITY;
        mx = fmaxf(mx, e[u]);
    }
#pragma unroll
    for (int off = 32; off > 0; off >>= 1) mx = fmaxf(mx, __shfl_xor(mx, off));
    __shared__ float red[8];
    if ((tid & 63) == 0) red[tid >> 6] = mx;
    __syncthreads();
    mx = fmaxf(fmaxf(red[0], red[1]), fmaxf(red[2], red[3]));

    const bool allmask = (mx == -INFINITY);
    const float mref = allmask ? 0.f : mx;
    float p[8];
    float sum = 0.f;
#pragma unroll
    for (int u = 0; u < 8; ++u) {
        p[u] = (e[u] == -INFINITY) ? 0.f : __expf(e[u] - mref);
        sum += p[u];
    }
#pragma unroll
    for (int off = 32; off > 0; off >>= 1) sum += __shfl_xor(sum, off);
    if ((tid & 63) == 0) red[4 + (tid >> 6)] = sum;
    __syncthreads();
    sum = red[4] + red[5] + red[6] + red[7];

    const float inv = 1.f / sum;
    f32x8 outv;
#pragma unroll
    for (int u = 0; u < 8; ++u) {
        outv[u] = allmask ? (1.f / 2048.f) : p[u] * inv;
    }
    *reinterpret_cast<f32x8*>(att + (long)bx * 2048 + j0) = outv;
}

// ---------------------------------------------------------------------------
extern "C" void kernel_launch(void* const* d_in, const int* in_sizes, int n_in,
                              void* d_out, int out_size, void* d_ws, size_t ws_size,
                              hipStream_t stream) {
    const float* x  = (const float*)d_in[0];   // [2048][512]
    const int* adj  = (const int*)d_in[1];     // [2048][2048]
    const float* W1 = (const float*)d_in[2];   // [8][512][64]
    const float* a1 = (const float*)d_in[3];   // [8][128]
    const float* W2 = (const float*)d_in[4];
    const float* a2 = (const float*)d_in[5];

    float* out  = (float*)d_out;       // h2 [2048][512]
    float* att1 = out + 1048576;       // [8][2048][2048]
    float* att2 = att1 + 33554432;

    char* w = (char*)d_ws;
    unsigned short* WpHi  = (unsigned short*)(w);             // 512 KB
    unsigned short* WpLo  = (unsigned short*)(w + 524288);    // 512 KB
    unsigned short* WhpHi = (unsigned short*)(w + 1048576);   // 2 MB
    unsigned short* WhpLo = (unsigned short*)(w + 3145728);   // 2 MB
    float* WhPl           = (float*)(w + 5242880);            // 4 MB
    float* s1             = (float*)(w + 9437184);            // 64 KB
    float* s2             = (float*)(w + 9502720);            // 64 KB
    float* x2             = (float*)(w + 9568256);            // 4 MB -> ends ~13.1 MB

    // ---- layer 1 ----
    reorder_w_kernel<<<1024, 256, 0, stream>>>(W1, WpHi, WpLo);
    gemm1_kernel<<<256, 256, 0, stream>>>(x, WpHi, WpLo, WhPl, WhpHi, WhpLo);
    s_kernel<<<64, 256, 0, stream>>>(WhPl, a1, s1, s2);
    softmax_kernel<<<16384, 256, 0, stream>>>(s1, s2, adj, att1);
    gemm2_kernel<<<256, 256, 0, stream>>>(att1, WhpHi, WhpLo, x2);

    // ---- layer 2 ----
    reorder_w_kernel<<<1024, 256, 0, stream>>>(W2, WpHi, WpLo);
    gemm1_kernel<<<256, 256, 0, stream>>>(x2, WpHi, WpLo, WhPl, WhpHi, WhpLo);
    s_kernel<<<64, 256, 0, stream>>>(WhPl, a2, s1, s2);
    softmax_kernel<<<16384, 256, 0, stream>>>(s1, s2, adj, att2);
    gemm2_kernel<<<256, 256, 0, stream>>>(att2, WhpHi, WhpLo, out);
}

// Round 4
// 576.706 us; speedup vs baseline: 1.1007x; 1.1007x over previous
//
#include <hip/hip_runtime.h>
#include <hip/hip_bf16.h>

// GAT (2-layer, 8-head) on gfx950. Inputs f32 (adj int32), outputs f32.
// d_out = [h2: 2048*512 | att1: 8*2048*2048 | att2: 8*2048*2048] float32.

typedef __attribute__((ext_vector_type(8))) short bf16x8;
typedef __attribute__((ext_vector_type(4))) float f32x4;

__device__ __forceinline__ float bf2f(unsigned short u) {
    return __uint_as_float(((unsigned int)u) << 16);
}
__device__ __forceinline__ unsigned short f2bf(float f) {
    __hip_bfloat16 h = __float2bfloat16(f);
    return __builtin_bit_cast(unsigned short, h);
}
__device__ __forceinline__ float elu1(float x) { return x > 0.f ? x : expm1f(x); }

// ---------------------------------------------------------------------------
// adj [2048][2048] int32 -> bitmask [2048][64] u32 (u64 stores, ballot).
// ---------------------------------------------------------------------------
__global__ __launch_bounds__(256) void adjbits_kernel(
    const int* __restrict__ adj, unsigned long long* __restrict__ gbits) {
    int g = blockIdx.x * 256 + threadIdx.x;  // 4194304 threads
    unsigned long long m = __ballot(adj[g] > 0);
    if ((threadIdx.x & 63) == 0) gbits[g >> 6] = m;
}

// ---------------------------------------------------------------------------
// Reorder W [8][512][64] (f32) into split-bf16 MFMA B-fragment packing:
// Wp{Hi,Lo}[h][kb][col][k&31], k = kb*32 + (quad*8+j).
// ---------------------------------------------------------------------------
__global__ __launch_bounds__(256) void reorder_w_kernel(
    const float* __restrict__ W, unsigned short* __restrict__ WpHi,
    unsigned short* __restrict__ WpLo) {
    int i = blockIdx.x * 256 + threadIdx.x;  // 262144 threads
    int o = i & 63;
    int k = (i >> 6) & 511;
    int h = i >> 15;
    float v = W[i];
    unsigned short hi = f2bf(v);
    unsigned short lo = f2bf(v - bf2f(hi));
    long idx = (((h * 16) + (k >> 5)) * 64 + o) * 32 + (k & 31);
    WpHi[idx] = hi;
    WpLo[idx] = lo;
}

// ---------------------------------------------------------------------------
// GEMM1: Wh[h] = A[2048][512](f32) @ W[h][512][64], split-bf16 (3 MFMAs).
// Epilogue: (a) s1/s2 = Wh·a_src/a_dst via in-register shfl reduction,
//           (b) store Wh as split-bf16 fragment-packed WhpHi/Lo.
// ---------------------------------------------------------------------------
__global__ __launch_bounds__(256) void gemm1_kernel(
    const float* __restrict__ A,
    const unsigned short* __restrict__ BpHi, const unsigned short* __restrict__ BpLo,
    const float* __restrict__ avec,
    unsigned short* __restrict__ WhpHi, unsigned short* __restrict__ WhpLo,
    float* __restrict__ s1, float* __restrict__ s2) {
    const int bx   = blockIdx.x;   // 256 = 8 heads * 32 mtiles
    const int h    = bx >> 5;
    const int mt   = bx & 31;
    const int tid  = threadIdx.x;
    const int wave = tid >> 6;
    const int lane = tid & 63;
    const int quad = lane >> 4;
    const int m16  = lane & 15;
    const int row0 = mt * 64 + wave * 16;

    const float* Arow = A + (long)(row0 + m16) * 512 + quad * 8;
    const long boff = ((long)h * 1024 + m16) * 32 + quad * 8;
    const unsigned short* BH = BpHi + boff;
    const unsigned short* BL = BpLo + boff;

    f32x4 acc[4];
#pragma unroll
    for (int t = 0; t < 4; ++t)
#pragma unroll
        for (int r = 0; r < 4; ++r) acc[t][r] = 0.f;

    for (int kb = 0; kb < 16; ++kb) {
        const float* ap = Arow + kb * 32;
        bf16x8 ahi, alo;
#pragma unroll
        for (int j = 0; j < 8; ++j) {
            float v = ap[j];
            unsigned short hv = f2bf(v);
            ahi[j] = (short)hv;
            alo[j] = (short)f2bf(v - bf2f(hv));
        }
        const unsigned short* bh0 = BH + (long)kb * 2048;
        const unsigned short* bl0 = BL + (long)kb * 2048;
#pragma unroll
        for (int t = 0; t < 4; ++t) {
            bf16x8 bh = *reinterpret_cast<const bf16x8*>(bh0 + t * 512);
            bf16x8 bl = *reinterpret_cast<const bf16x8*>(bl0 + t * 512);
            acc[t] = __builtin_amdgcn_mfma_f32_16x16x32_bf16(alo, bh, acc[t], 0, 0, 0);
            acc[t] = __builtin_amdgcn_mfma_f32_16x16x32_bf16(ahi, bl, acc[t], 0, 0, 0);
            acc[t] = __builtin_amdgcn_mfma_f32_16x16x32_bf16(ahi, bh, acc[t], 0, 0, 0);
        }
    }

    // ---- s1/s2 epilogue: reduce acc rows against a_src / a_dst ----
    float aS[4], aD[4];
#pragma unroll
    for (int t = 0; t < 4; ++t) {
        aS[t] = avec[(h << 7) + t * 16 + m16];
        aD[t] = avec[(h << 7) + 64 + t * 16 + m16];
    }
#pragma unroll
    for (int r = 0; r < 4; ++r) {
        float t1 = 0.f, t2 = 0.f;
#pragma unroll
        for (int t = 0; t < 4; ++t) {
            float v = acc[t][r];
            t1 = fmaf(v, aS[t], t1);
            t2 = fmaf(v, aD[t], t2);
        }
#pragma unroll
        for (int off = 1; off < 16; off <<= 1) {
            t1 += __shfl_xor(t1, off);
            t2 += __shfl_xor(t2, off);
        }
        if (m16 == 0) {
            int row = row0 + quad * 4 + r;
            s1[(h << 11) + row] = t1;
            s2[(h << 11) + row] = t2;
        }
    }

    // ---- store Wh split-bf16 fragment-packed ----
#pragma unroll
    for (int t = 0; t < 4; ++t) {
        const int col = t * 16 + m16;
#pragma unroll
        for (int r = 0; r < 4; ++r) {
            const int row = row0 + quad * 4 + r;
            const float v = acc[t][r];
            long idx = (((long)(h * 64 + (row >> 5)) * 64 + col) << 5) + (row & 31);
            unsigned short hv = f2bf(v);
            WhpHi[idx] = hv;
            WhpLo[idx] = f2bf(v - bf2f(hv));
        }
    }
}

// ---------------------------------------------------------------------------
// Fused attention: softmax (2-pass, online m/l) + att write + PV MFMA.
// Block = 128 thr (2 waves), 32 rows; grid = 8 heads * 64 row-tiles = 512.
// ---------------------------------------------------------------------------
#define COMPUTE_E()                                                            \
    unsigned int word = lbits[lrow * 66 + jt];                                 \
    float4 sa = *reinterpret_cast<const float4*>(ls2 + jt * 32 + quad * 8);    \
    float4 sb = *reinterpret_cast<const float4*>(ls2 + jt * 32 + quad * 8 + 4);\
    float e[8];                                                                \
    {                                                                          \
        float s2v[8] = {sa.x, sa.y, sa.z, sa.w, sb.x, sb.y, sb.z, sb.w};       \
        _Pragma("unroll") for (int u = 0; u < 8; ++u) {                        \
            float ev = s1i + s2v[u];                                           \
            ev = fmaxf(ev, 0.2f * ev); /* leakyrelu */                         \
            e[u] = ((word >> (quad * 8 + u)) & 1u) ? ev : -INFINITY;           \
        }                                                                      \
    }

__global__ __launch_bounds__(128) void fused_att_kernel(
    const float* __restrict__ s1g, const float* __restrict__ s2g,
    const unsigned int* __restrict__ gbits,
    const unsigned short* __restrict__ WhpHi, const unsigned short* __restrict__ WhpLo,
    float* __restrict__ att, float* __restrict__ hout) {
    __shared__ unsigned int lbits[32 * 66];  // +2 pad words/row: conflict-free
    __shared__ float ls2[2048];
    const int bx   = blockIdx.x;   // 512
    const int h    = bx >> 6;
    const int row0 = (bx & 63) << 5;
    const int tid  = threadIdx.x;
    const int wave = tid >> 6;
    const int lane = tid & 63;
    const int quad = lane >> 4;
    const int m16  = lane & 15;

    // stage adj bits (32 rows x 64 words) and s2 (2048 f32) into LDS
#pragma unroll
    for (int i = 0; i < 16; ++i) {
        int linear = i * 128 + tid;
        int r = linear >> 6, w2 = linear & 63;
        lbits[r * 66 + w2] = gbits[(row0 + r) * 64 + w2];
    }
    const float* s2h = s2g + (h << 11);
#pragma unroll
    for (int i = 0; i < 4; ++i) {
        int idx = i * 128 + tid;
        reinterpret_cast<float4*>(ls2)[idx] = reinterpret_cast<const float4*>(s2h)[idx];
    }
    __syncthreads();

    const int lrow = (wave << 4) + m16;  // 0..31 (A-fragment row = lane&15)
    const int grow = row0 + lrow;
    const float s1i = s1g[(h << 11) + grow];

    // ---- pass 1: per-lane online (m,l) over this lane's j-slice ----
    float m = -INFINITY, l = 0.f;
    for (int jt = 0; jt < 64; ++jt) {
        COMPUTE_E();
        float c = fmaxf(fmaxf(fmaxf(e[0], e[1]), fmaxf(e[2], e[3])),
                        fmaxf(fmaxf(e[4], e[5]), fmaxf(e[6], e[7])));
        float mn = fmaxf(m, c);
        float alpha = (m == -INFINITY) ? 0.f : __expf(m - mn);
        float s = 0.f;
#pragma unroll
        for (int u = 0; u < 8; ++u)
            s += (e[u] == -INFINITY) ? 0.f : __expf(e[u] - mn);
        l = fmaf(l, alpha, s);
        m = mn;
    }
    // merge across the 4 lanes (quads) sharing this row
#pragma unroll
    for (int off = 16; off < 64; off <<= 1) {
        float mo  = __shfl_xor(m, off);
        float lo2 = __shfl_xor(l, off);
        float mn  = fmaxf(m, mo);
        float t1 = (m  == -INFINITY) ? 0.f : l   * __expf(m  - mn);
        float t2 = (mo == -INFINITY) ? 0.f : lo2 * __expf(mo - mn);
        l = t1 + t2;
        m = mn;
    }

    const bool  am    = (m == -INFINITY);
    const float invl  = am ? 0.f : 1.f / l;
    const float fallb = 1.f / 2048.f;

    // ---- pass 2: recompute e, write normalized att, MFMA accumulate ----
    f32x4 acc[4];
#pragma unroll
    for (int t = 0; t < 4; ++t)
#pragma unroll
        for (int r = 0; r < 4; ++r) acc[t][r] = 0.f;

    const long boff = ((long)(h << 12) + m16) * 32 + quad * 8;
    const unsigned short* BH = WhpHi + boff;
    const unsigned short* BL = WhpLo + boff;
    float* attrow = att + (long)h * 4194304 + (long)grow * 2048;

    for (int jt = 0; jt < 64; ++jt) {
        COMPUTE_E();
        float p[8];
#pragma unroll
        for (int u = 0; u < 8; ++u) {
            float pv = (e[u] == -INFINITY) ? 0.f : __expf(e[u] - m) * invl;
            p[u] = am ? fallb : pv;
        }
        float* ap = attrow + jt * 32 + quad * 8;
        *reinterpret_cast<float4*>(ap)     = make_float4(p[0], p[1], p[2], p[3]);
        *reinterpret_cast<float4*>(ap + 4) = make_float4(p[4], p[5], p[6], p[7]);

        bf16x8 ahi, alo;
#pragma unroll
        for (int u = 0; u < 8; ++u) {
            unsigned short hv = f2bf(p[u]);
            ahi[u] = (short)hv;
            alo[u] = (short)f2bf(p[u] - bf2f(hv));
        }
        const unsigned short* bh0 = BH + (long)jt * 2048;
        const unsigned short* bl0 = BL + (long)jt * 2048;
#pragma unroll
        for (int t = 0; t < 4; ++t) {
            bf16x8 bh = *reinterpret_cast<const bf16x8*>(bh0 + t * 512);
            bf16x8 bl = *reinterpret_cast<const bf16x8*>(bl0 + t * 512);
            acc[t] = __builtin_amdgcn_mfma_f32_16x16x32_bf16(alo, bh, acc[t], 0, 0, 0);
            acc[t] = __builtin_amdgcn_mfma_f32_16x16x32_bf16(ahi, bl, acc[t], 0, 0, 0);
            acc[t] = __builtin_amdgcn_mfma_f32_16x16x32_bf16(ahi, bh, acc[t], 0, 0, 0);
        }
    }

    // epilogue: h' -> elu(elu()) -> hout[row*512 + h*64 + col]
#pragma unroll
    for (int t = 0; t < 4; ++t) {
        const int col = (t << 4) + m16;
#pragma unroll
        for (int r = 0; r < 4; ++r) {
            const int row = row0 + (wave << 4) + (quad << 2) + r;
            hout[(row << 9) + (h << 6) + col] = elu1(elu1(acc[t][r]));
        }
    }
}

// ---------------------------------------------------------------------------
extern "C" void kernel_launch(void* const* d_in, const int* in_sizes, int n_in,
                              void* d_out, int out_size, void* d_ws, size_t ws_size,
                              hipStream_t stream) {
    const float* x  = (const float*)d_in[0];   // [2048][512]
    const int* adj  = (const int*)d_in[1];     // [2048][2048]
    const float* W1 = (const float*)d_in[2];   // [8][512][64]
    const float* a1 = (const float*)d_in[3];   // [8][128]
    const float* W2 = (const float*)d_in[4];
    const float* a2 = (const float*)d_in[5];

    float* out  = (float*)d_out;       // h2 [2048][512]
    float* att1 = out + 1048576;       // [8][2048][2048]
    float* att2 = att1 + 33554432;

    char* w = (char*)d_ws;
    unsigned short* WpHi  = (unsigned short*)(w);             // 512 KB
    unsigned short* WpLo  = (unsigned short*)(w + 524288);    // 512 KB
    unsigned short* WhpHi = (unsigned short*)(w + 1048576);   // 2 MB
    unsigned short* WhpLo = (unsigned short*)(w + 3145728);   // 2 MB
    float* s1             = (float*)(w + 5242880);            // 64 KB
    float* s2             = (float*)(w + 5308416);            // 64 KB
    unsigned long long* gbits = (unsigned long long*)(w + 5373952);  // 512 KB
    float* x2             = (float*)(w + 5898240);            // 4 MB -> ends ~9.6 MB

    const unsigned int* gbits32 = (const unsigned int*)gbits;

    adjbits_kernel<<<16384, 256, 0, stream>>>(adj, gbits);

    // ---- layer 1 ----
    reorder_w_kernel<<<1024, 256, 0, stream>>>(W1, WpHi, WpLo);
    gemm1_kernel<<<256, 256, 0, stream>>>(x, WpHi, WpLo, a1, WhpHi, WhpLo, s1, s2);
    fused_att_kernel<<<512, 128, 0, stream>>>(s1, s2, gbits32, WhpHi, WhpLo, att1, x2);

    // ---- layer 2 ----
    reorder_w_kernel<<<1024, 256, 0, stream>>>(W2, WpHi, WpLo);
    gemm1_kernel<<<256, 256, 0, stream>>>(x2, WpHi, WpLo, a2, WhpHi, WhpLo, s1, s2);
    fused_att_kernel<<<512, 128, 0, stream>>>(s1, s2, gbits32, WhpHi, WhpLo, att2, out);
}

// Round 5
// 381.805 us; speedup vs baseline: 1.6625x; 1.5105x over previous
//
#include <hip/hip_runtime.h>
#include <hip/hip_bf16.h>

// GAT (2-layer, 8-head) on gfx950. Inputs f32 (adj int32), outputs f32.
// d_out = [h2: 2048*512 | att1: 8*2048*2048 | att2: 8*2048*2048] float32.

typedef __attribute__((ext_vector_type(8))) short bf16x8;
typedef __attribute__((ext_vector_type(4))) float f32x4;

__device__ __forceinline__ float bf2f(unsigned short u) {
    return __uint_as_float(((unsigned int)u) << 16);
}
__device__ __forceinline__ unsigned short f2bf(float f) {
    __hip_bfloat16 h = __float2bfloat16(f);
    return __builtin_bit_cast(unsigned short, h);
}
__device__ __forceinline__ float elu1(float x) { return x > 0.f ? x : expm1f(x); }

// ---------------------------------------------------------------------------
// adj [2048][2048] int32 -> bitmask [2048][64] u32 (u64 stores via ballot).
// ---------------------------------------------------------------------------
__global__ __launch_bounds__(256) void adjbits_kernel(
    const int* __restrict__ adj, unsigned long long* __restrict__ gbits) {
    int g = blockIdx.x * 256 + threadIdx.x;  // 4194304 threads
    unsigned long long m = __ballot(adj[g] > 0);
    if ((threadIdx.x & 63) == 0) gbits[g >> 6] = m;
}

// ---------------------------------------------------------------------------
// Reorder W [8][512][64] (f32) into split-bf16 MFMA B-fragment packing:
// Wp{Hi,Lo}[h][kb][col][k&31], k = kb*32 + (quad*8+j).
// ---------------------------------------------------------------------------
__global__ __launch_bounds__(256) void reorder_w_kernel(
    const float* __restrict__ W, unsigned short* __restrict__ WpHi,
    unsigned short* __restrict__ WpLo) {
    int i = blockIdx.x * 256 + threadIdx.x;  // 262144 threads
    int o = i & 63;
    int k = (i >> 6) & 511;
    int h = i >> 15;
    float v = W[i];
    unsigned short hi = f2bf(v);
    unsigned short lo = f2bf(v - bf2f(hi));
    long idx = (((h * 16) + (k >> 5)) * 64 + o) * 32 + (k & 31);
    WpHi[idx] = hi;
    WpLo[idx] = lo;
}

// ---------------------------------------------------------------------------
// GEMM1: Wh[h] = A[2048][512](f32) @ W[h][512][64], split-bf16 (3 MFMAs).
// 2-way K-split: block = 4 waves over (2 row-halves x 2 K-halves), 32 rows.
// Grid = 8 heads * 64 row-tiles = 512 blocks. LDS-reduce K partials.
// Epilogue (kw==0 waves): s1/s2 shfl-reduction + bf16 fragment-packed Whp.
// ---------------------------------------------------------------------------
__global__ __launch_bounds__(256, 2) void gemm1_kernel(
    const float* __restrict__ A,
    const unsigned short* __restrict__ BpHi, const unsigned short* __restrict__ BpLo,
    const float* __restrict__ avec,
    unsigned short* __restrict__ Whp, float* __restrict__ s1, float* __restrict__ s2) {
    __shared__ float accred[2][64][20];  // [rowhalf][col][16 rows + pad] (16B-aligned rows)
    const int bx   = blockIdx.x;   // 512
    const int h    = bx >> 6;
    const int mt   = bx & 63;
    const int tid  = threadIdx.x;
    const int wave = tid >> 6;
    const int lane = tid & 63;
    const int quad = lane >> 4;
    const int m16  = lane & 15;
    const int rw   = wave & 1;   // row half (16 rows each)
    const int kw   = wave >> 1;  // K half (256 each)
    const int rowbase = mt * 32 + rw * 16;

    const float* Arow = A + (long)(rowbase + m16) * 512 + kw * 256 + quad * 8;
    const long boff = ((long)(h * 16 + kw * 8) * 64 + m16) * 32 + quad * 8;
    const unsigned short* BH = BpHi + boff;
    const unsigned short* BL = BpLo + boff;

    f32x4 acc[4];
#pragma unroll
    for (int t = 0; t < 4; ++t)
#pragma unroll
        for (int r = 0; r < 4; ++r) acc[t][r] = 0.f;

    for (int kb = 0; kb < 8; ++kb) {
        const float* ap = Arow + kb * 32;
        bf16x8 ahi, alo;
#pragma unroll
        for (int j = 0; j < 8; ++j) {
            float v = ap[j];
            unsigned short hv = f2bf(v);
            ahi[j] = (short)hv;
            alo[j] = (short)f2bf(v - bf2f(hv));
        }
        const unsigned short* bh0 = BH + (long)kb * 2048;
        const unsigned short* bl0 = BL + (long)kb * 2048;
#pragma unroll
        for (int t = 0; t < 4; ++t) {
            bf16x8 bh = *reinterpret_cast<const bf16x8*>(bh0 + t * 512);
            bf16x8 bl = *reinterpret_cast<const bf16x8*>(bl0 + t * 512);
            acc[t] = __builtin_amdgcn_mfma_f32_16x16x32_bf16(alo, bh, acc[t], 0, 0, 0);
            acc[t] = __builtin_amdgcn_mfma_f32_16x16x32_bf16(ahi, bl, acc[t], 0, 0, 0);
            acc[t] = __builtin_amdgcn_mfma_f32_16x16x32_bf16(ahi, bh, acc[t], 0, 0, 0);
        }
    }

    if (kw == 1) {
#pragma unroll
        for (int t = 0; t < 4; ++t)
            *reinterpret_cast<f32x4*>(&accred[rw][t * 16 + m16][quad * 4]) = acc[t];
    }
    __syncthreads();
    if (kw == 1) return;

#pragma unroll
    for (int t = 0; t < 4; ++t) {
        f32x4 o = *reinterpret_cast<const f32x4*>(&accred[rw][t * 16 + m16][quad * 4]);
#pragma unroll
        for (int r = 0; r < 4; ++r) acc[t][r] += o[r];
    }

    // ---- s1/s2 epilogue ----
    float aS[4], aD[4];
#pragma unroll
    for (int t = 0; t < 4; ++t) {
        aS[t] = avec[(h << 7) + t * 16 + m16];
        aD[t] = avec[(h << 7) + 64 + t * 16 + m16];
    }
#pragma unroll
    for (int r = 0; r < 4; ++r) {
        float t1 = 0.f, t2 = 0.f;
#pragma unroll
        for (int t = 0; t < 4; ++t) {
            float v = acc[t][r];
            t1 = fmaf(v, aS[t], t1);
            t2 = fmaf(v, aD[t], t2);
        }
#pragma unroll
        for (int off = 1; off < 16; off <<= 1) {
            t1 += __shfl_xor(t1, off);
            t2 += __shfl_xor(t2, off);
        }
        if (m16 == 0) {
            int row = rowbase + quad * 4 + r;
            s1[(h << 11) + row] = t1;
            s2[(h << 11) + row] = t2;
        }
    }

    // ---- store Wh bf16 fragment-packed (Hi only; PV tolerates bf16) ----
#pragma unroll
    for (int t = 0; t < 4; ++t) {
        const int col = t * 16 + m16;
#pragma unroll
        for (int r = 0; r < 4; ++r) {
            const int row = rowbase + quad * 4 + r;
            long idx = (((long)(h * 64 + (row >> 5)) * 64 + col) << 5) + (row & 31);
            Whp[idx] = f2bf(acc[t][r]);
        }
    }
}

// ---------------------------------------------------------------------------
// Fused attention: masked-max (monotone-lrelu trick) + denom + att write + PV.
// Block = 256 thr (4 waves), 16 rows; each wave owns a j-quarter (16 words).
// Grid = 8 heads * 128 row-tiles = 1024 blocks -> 4096 waves (4/SIMD).
// ---------------------------------------------------------------------------
__global__ __launch_bounds__(256, 4) void fused_att_kernel(
    const float* __restrict__ s1g, const float* __restrict__ s2g,
    const unsigned int* __restrict__ gbits,
    const unsigned short* __restrict__ Whp,
    float* __restrict__ att, float* __restrict__ hout) {
    __shared__ unsigned int lbits[16 * 65];   // 16 rows x 64 words, +1 pad
    __shared__ float ls2[2048];
    __shared__ float lmax[4][16];
    __shared__ float lsum[4][16];
    __shared__ float accred[3][64][20];       // waves 1..3 partial PV

    const int bx   = blockIdx.x;   // 1024
    const int h    = bx >> 7;
    const int row0 = (bx & 127) << 4;
    const int tid  = threadIdx.x;
    const int wq   = tid >> 6;     // wave = j-quarter
    const int lane = tid & 63;
    const int quad = lane >> 4;
    const int m16  = lane & 15;

    // stage adj bits (16 rows x 64 words) + s2 (2048 f32)
#pragma unroll
    for (int i = 0; i < 4; ++i) {
        int idx = i * 256 + tid;
        lbits[(idx >> 6) * 65 + (idx & 63)] = gbits[((row0 + (idx >> 6)) << 6) + (idx & 63)];
    }
    const float4* s2v4 = reinterpret_cast<const float4*>(s2g + (h << 11));
#pragma unroll
    for (int i = 0; i < 2; ++i) {
        int idx = i * 256 + tid;
        reinterpret_cast<float4*>(ls2)[idx] = s2v4[idx];
    }
    __syncthreads();

    const float s1i = s1g[(h << 11) + row0 + m16];

    // ---- P1: masked max of s2 over this wave's 16 words ----
    float mx = -INFINITY;
    for (int i = 0; i < 16; ++i) {
        const int jt = wq * 16 + i;
        unsigned int word = lbits[m16 * 65 + jt];
        float4 sa = *reinterpret_cast<const float4*>(ls2 + jt * 32 + quad * 8);
        float4 sb = *reinterpret_cast<const float4*>(ls2 + jt * 32 + quad * 8 + 4);
        float sv[8] = {sa.x, sa.y, sa.z, sa.w, sb.x, sb.y, sb.z, sb.w};
#pragma unroll
        for (int u = 0; u < 8; ++u)
            mx = fmaxf(mx, ((word >> (quad * 8 + u)) & 1u) ? sv[u] : -INFINITY);
    }
    mx = fmaxf(mx, __shfl_xor(mx, 16));
    mx = fmaxf(mx, __shfl_xor(mx, 32));
    if (lane < 16) lmax[wq][m16] = mx;
    __syncthreads();
    const float Ms2 = fmaxf(fmaxf(lmax[0][m16], lmax[1][m16]),
                            fmaxf(lmax[2][m16], lmax[3][m16]));
    const float ebar = s1i + Ms2;              // -inf if row all-masked
    const float m = fmaxf(ebar, 0.2f * ebar);  // lrelu (monotone) of max = max of lrelu
    const bool am = (m == -INFINITY);

    // ---- P2: l = sum of exp(e-m) over allowed j ----
    float lp = 0.f;
    for (int i = 0; i < 16; ++i) {
        const int jt = wq * 16 + i;
        unsigned int word = lbits[m16 * 65 + jt];
        float4 sa = *reinterpret_cast<const float4*>(ls2 + jt * 32 + quad * 8);
        float4 sb = *reinterpret_cast<const float4*>(ls2 + jt * 32 + quad * 8 + 4);
        float sv[8] = {sa.x, sa.y, sa.z, sa.w, sb.x, sb.y, sb.z, sb.w};
#pragma unroll
        for (int u = 0; u < 8; ++u) {
            float e = s1i + sv[u];
            e = fmaxf(e, 0.2f * e);
            lp += ((word >> (quad * 8 + u)) & 1u) ? __expf(e - m) : 0.f;
        }
    }
    lp += __shfl_xor(lp, 16);
    lp += __shfl_xor(lp, 32);
    if (lane < 16) lsum[wq][m16] = lp;
    __syncthreads();
    const float l = lsum[0][m16] + lsum[1][m16] + lsum[2][m16] + lsum[3][m16];
    const float invl = am ? 0.f : 1.f / l;
    const float fallb = 1.f / 2048.f;

    // ---- P3: att write + PV MFMA over this wave's j-quarter ----
    f32x4 acc[4];
#pragma unroll
    for (int t = 0; t < 4; ++t)
#pragma unroll
        for (int r = 0; r < 4; ++r) acc[t][r] = 0.f;

    const unsigned short* BW = Whp + ((long)(h << 12) + m16) * 32 + quad * 8;
    float* attrow = att + (long)h * 4194304 + (long)(row0 + m16) * 2048;

    for (int i = 0; i < 16; ++i) {
        const int jt = wq * 16 + i;
        unsigned int word = lbits[m16 * 65 + jt];
        float4 sa = *reinterpret_cast<const float4*>(ls2 + jt * 32 + quad * 8);
        float4 sb = *reinterpret_cast<const float4*>(ls2 + jt * 32 + quad * 8 + 4);
        float sv[8] = {sa.x, sa.y, sa.z, sa.w, sb.x, sb.y, sb.z, sb.w};
        float p[8];
        bf16x8 af;
#pragma unroll
        for (int u = 0; u < 8; ++u) {
            float e = s1i + sv[u];
            e = fmaxf(e, 0.2f * e);
            float pv = ((word >> (quad * 8 + u)) & 1u) ? __expf(e - m) * invl : 0.f;
            p[u] = am ? fallb : pv;
            af[u] = (short)f2bf(p[u]);
        }
        float* ap = attrow + jt * 32 + quad * 8;
        *reinterpret_cast<float4*>(ap)     = make_float4(p[0], p[1], p[2], p[3]);
        *reinterpret_cast<float4*>(ap + 4) = make_float4(p[4], p[5], p[6], p[7]);

        const unsigned short* b0 = BW + (long)jt * 2048;
#pragma unroll
        for (int t = 0; t < 4; ++t) {
            bf16x8 bf = *reinterpret_cast<const bf16x8*>(b0 + t * 512);
            acc[t] = __builtin_amdgcn_mfma_f32_16x16x32_bf16(af, bf, acc[t], 0, 0, 0);
        }
    }

    // ---- reduce partial PV across waves, epilogue by wave 0 ----
    if (wq > 0) {
#pragma unroll
        for (int t = 0; t < 4; ++t)
            *reinterpret_cast<f32x4*>(&accred[wq - 1][t * 16 + m16][quad * 4]) = acc[t];
    }
    __syncthreads();
    if (wq == 0) {
#pragma unroll
        for (int t = 0; t < 4; ++t) {
            const int col = t * 16 + m16;
#pragma unroll
            for (int w = 0; w < 3; ++w) {
                f32x4 o = *reinterpret_cast<const f32x4*>(&accred[w][col][quad * 4]);
#pragma unroll
                for (int r = 0; r < 4; ++r) acc[t][r] += o[r];
            }
#pragma unroll
            for (int r = 0; r < 4; ++r) {
                const int row = row0 + quad * 4 + r;
                hout[(row << 9) + (h << 6) + col] = elu1(elu1(acc[t][r]));
            }
        }
    }
}

// ---------------------------------------------------------------------------
extern "C" void kernel_launch(void* const* d_in, const int* in_sizes, int n_in,
                              void* d_out, int out_size, void* d_ws, size_t ws_size,
                              hipStream_t stream) {
    const float* x  = (const float*)d_in[0];   // [2048][512]
    const int* adj  = (const int*)d_in[1];     // [2048][2048]
    const float* W1 = (const float*)d_in[2];   // [8][512][64]
    const float* a1 = (const float*)d_in[3];   // [8][128]
    const float* W2 = (const float*)d_in[4];
    const float* a2 = (const float*)d_in[5];

    float* out  = (float*)d_out;       // h2 [2048][512]
    float* att1 = out + 1048576;       // [8][2048][2048]
    float* att2 = att1 + 33554432;

    char* w = (char*)d_ws;
    unsigned short* WpHi  = (unsigned short*)(w);             // 512 KB
    unsigned short* WpLo  = (unsigned short*)(w + 524288);    // 512 KB
    unsigned short* Whp   = (unsigned short*)(w + 1048576);   // 2 MB
    float* s1             = (float*)(w + 3145728);            // 64 KB
    float* s2             = (float*)(w + 3211264);            // 64 KB
    unsigned long long* gbits = (unsigned long long*)(w + 3276800);  // 512 KB
    float* x2             = (float*)(w + 3801088);            // 4 MB -> ends ~7.8 MB

    const unsigned int* gbits32 = (const unsigned int*)gbits;

    adjbits_kernel<<<16384, 256, 0, stream>>>(adj, gbits);

    // ---- layer 1 ----
    reorder_w_kernel<<<1024, 256, 0, stream>>>(W1, WpHi, WpLo);
    gemm1_kernel<<<512, 256, 0, stream>>>(x, WpHi, WpLo, a1, Whp, s1, s2);
    fused_att_kernel<<<1024, 256, 0, stream>>>(s1, s2, gbits32, Whp, att1, x2);

    // ---- layer 2 ----
    reorder_w_kernel<<<1024, 256, 0, stream>>>(W2, WpHi, WpLo);
    gemm1_kernel<<<512, 256, 0, stream>>>(x2, WpHi, WpLo, a2, Whp, s1, s2);
    fused_att_kernel<<<1024, 256, 0, stream>>>(s1, s2, gbits32, Whp, att2, out);
}